// Round 5
// baseline (403.948 us; speedup 1.0000x reference)
//
#include <hip/hip_runtime.h>
#include <stdint.h>
#include <math.h>

#define NALPH 128
#define NEMB  128
#define NST   512
#define BATCH 256
#define TLEN  256
#define FANIN 640   // NEMB + NST

// No host/device-divergent preprocessor control flow (R11 lesson).
#define SDOT4(a, b, c) __builtin_amdgcn_sdot4((a), (b), (c), false)
typedef __attribute__((ext_vector_type(4))) int i32x4;

// ---------------------------------------------------------------------------
// k_prep (896 blocks x 256 thr) — unchanged from R12:
//  [0,256)    G[tok*512+n] = b_in[n] + sum_e emb[tok,e]*W_in[n,e]  (fp32 exact)
//  [256,768)  W_s row-quant: WqT[kg*512+n] (dword layout; k_rec stages the
//             k>=256 half into LDS) AND MFMA B-frag order
//             WsF[((nt*8+c)*64+lane)*4+d]; Sd[n]=mx/16129
//  [768,896)  W_out row-quant: WoQ[j*128+a] (k_out_i8 layout); So[a]=mx/16129
// ---------------------------------------------------------------------------
__global__ __launch_bounds__(256) void k_prep(
    const float* __restrict__ emb, const float* __restrict__ W_in,
    const float* __restrict__ b_in, const float* __restrict__ W_out,
    float* __restrict__ G, int* __restrict__ WqT, float* __restrict__ Sd,
    int* __restrict__ WoQ, float* __restrict__ So, int* __restrict__ WsF)
{
  int bid = blockIdx.x, tid = threadIdx.x;
  if (bid < 256) {
    int idx = bid * 256 + tid;           // tok*512 + n
    int tok = idx >> 9, n = idx & 511;
    const float* er = emb + tok * NEMB;
    const float* wr = W_in + (size_t)n * FANIN;
    float acc = b_in[n];
#pragma unroll 8
    for (int e = 0; e < NEMB; ++e) acc += er[e] * wr[e];
    G[idx] = acc;
  } else if (bid < 768) {
    int n = bid - 256;                   // W_s row
    __shared__ float smax[128];
    float lw[4]; float m = 0.f;
    if (tid < 128) {
      const float* wr = W_in + (size_t)n * FANIN + NEMB + tid * 4;
#pragma unroll
      for (int i = 0; i < 4; ++i) { lw[i] = wr[i]; m = fmaxf(m, fabsf(lw[i])); }
      smax[tid] = m;
    }
    __syncthreads();
    for (int s2 = 64; s2 > 0; s2 >>= 1) {
      if (tid < s2) smax[tid] = fmaxf(smax[tid], smax[tid + s2]);
      __syncthreads();
    }
    float mx = smax[0];
    if (tid < 128) {
      float r = 127.f / mx;
      uint32_t pk = 0;
#pragma unroll
      for (int i = 0; i < 4; ++i) {
        int qv = (int)rintf(lw[i] * r);
        qv = qv < -127 ? -127 : (qv > 127 ? 127 : qv);
        pk |= (uint32_t)(qv & 0xff) << (8 * i);
      }
      WqT[tid * NST + n] = (int)pk;      // dword layout
      int kd = tid;
      int c = kd >> 4, hi = (kd >> 2) & 3, d = kd & 3;
      int lane = hi * 16 + (n & 15), nt = n >> 4;
      WsF[(((nt * 8 + c) * 64) + lane) * 4 + d] = (int)pk;  // MFMA B-frag
    }
    if (tid == 0) Sd[n] = mx / 16129.0f;
  } else {
    int a = bid - 768;                   // W_out row
    __shared__ float smax[128];
    float lw[4]; float m = 0.f;
    if (tid < 128) {
      const float* wr = W_out + (size_t)a * NST + tid * 4;
#pragma unroll
      for (int i = 0; i < 4; ++i) { lw[i] = wr[i]; m = fmaxf(m, fabsf(lw[i])); }
      smax[tid] = m;
    }
    __syncthreads();
    for (int s2 = 64; s2 > 0; s2 >>= 1) {
      if (tid < s2) smax[tid] = fmaxf(smax[tid], smax[tid + s2]);
      __syncthreads();
    }
    float mx = smax[0];
    if (tid < 128) {
      float r = 127.f / mx;
      uint32_t pk = 0;
#pragma unroll
      for (int i = 0; i < 4; ++i) {
        int qv = (int)rintf(lw[i] * r);
        qv = qv < -127 ? -127 : (qv > 127 ? 127 : qv);
        pk |= (uint32_t)(qv & 0xff) << (8 * i);
      }
      WoQ[tid * 128 + a] = (int)pk;      // k_out_i8 layout
    }
    if (tid == 0) So[a] = mx / 16129.0f;
  }
}

// ---------------------------------------------------------------------------
// k_rec R13 — HYBRID K-SPLIT: matrix pipe + VALU pipe in parallel.
// 256 blocks x 512 thr (8 waves, 2/SIMD), thread tid <-> state row n=tid.
//  k in [0,256):  MFMA. Wave wv owns n-tiles q=0..3 (n=wv*64+q*16+l15);
//                 B-frags Bf[4][4] = 64 dwords, AGPR residency FREE for MFMA
//                 (the R8-R10 parking tax applied only to v_dot4 operands).
//                 16 mfma/wave/step = 653 cyc/SIMD on the matrix pipe.
//  k in [256,512): sdot4, weights streamed from LDS every step — no register
//                 residency, so nothing to park. 512 rows x 16 int4, row
//                 stride 68 dwords (pad 4) -> b128 reads bank-conflict-free
//                 (bank start = ((tid%8)+jj)%8 group). 64 sdot/thread =
//                 256 cyc/SIMD on VALU. Pipes overlap (m114).
// Merge is lane-local: rows of D are replicated, so lane (hi,l15)'s own
// n (= wv*64+hi*16+l15 = tid) is acc tile q=hi, reg 0, col l15 -> 3-cndmask
// select, no cross-lane traffic. Integer totals identical to R8/R12 ->
// absmax must stay exactly 0.009765625.
// Epilogue all-64-lane parallel (R12 ran it on 16/64 lanes).
// LDS: 136 KB weights + 1 KB state ping-pong = 137 KB < 160 KB/CU.
// ---------------------------------------------------------------------------
__global__ __launch_bounds__(512, 2) void k_rec(
    const int* __restrict__ w, const float* __restrict__ G,
    const int* __restrict__ WqT, const int* __restrict__ WsF,
    const float* __restrict__ Sd, signed char* __restrict__ qstates)
{
  __shared__ __align__(16) int wlds[512 * 68];       // 136 KB, stride 68 (pad)
  __shared__ __align__(16) signed char qs[2][NST];   // 1 KB ping-pong
  int tid  = threadIdx.x;
  int lane = tid & 63, wv = tid >> 6;
  int l15  = lane & 15, hi = lane >> 4;
  int row  = blockIdx.x;

  // Stage the k in [256,512) weight half into LDS (one-time).
  // Thread tid owns row n=tid: dwords j = 64+jj*4+e, coalesced across tid.
  {
    int4* wp = (int4*)&wlds[tid * 68];
#pragma unroll
    for (int jj = 0; jj < 16; ++jj) {
      int4 v;
      v.x = WqT[(64 + jj * 4 + 0) * NST + tid];
      v.y = WqT[(64 + jj * 4 + 1) * NST + tid];
      v.z = WqT[(64 + jj * 4 + 2) * NST + tid];
      v.w = WqT[(64 + jj * 4 + 3) * NST + tid];
      wp[jj] = v;
    }
  }

  // MFMA B-frags, chunks c=0..3 only (k<256); same frag order proven in R12.
  const i32x4* wsf = (const i32x4*)WsF;
  i32x4 Bf[4][4];
#pragma unroll
  for (int q = 0; q < 4; ++q)
#pragma unroll
    for (int c = 0; c < 4; ++c)
      Bf[q][c] = wsf[((size_t)((wv * 4 + q) * 8 + c)) * 64 + lane];

  float dn = Sd[tid];
  const int* wr = w + row * TLEN;
  float g = G[wr[0] * NST + tid];

  qs[0][tid] = 0;
  __syncthreads();

  signed char* qrow = qstates + (size_t)row * TLEN * NST + tid;
  const int4* wp = (const int4*)&wlds[tid * 68];

  int p = 0;
  for (int t = 0; t < TLEN; ++t) {
    int tok_n = (t < TLEN - 1) ? wr[t + 1] : 0;
    float g_n = G[tok_n * NST + tid];    // prefetch next step's fin

    // --- MFMA half: A chunks c=0..3, bytes [c*64 + hi*16, +16) ---
    i32x4 A[4];
#pragma unroll
    for (int c = 0; c < 4; ++c)
      A[c] = *(const i32x4*)(qs[p] + c * 64 + hi * 16);
    i32x4 acc0 = {0,0,0,0}, acc1 = {0,0,0,0}, acc2 = {0,0,0,0}, acc3 = {0,0,0,0};
#pragma unroll
    for (int c = 0; c < 4; ++c) {
      acc0 = __builtin_amdgcn_mfma_i32_16x16x64_i8(A[c], Bf[0][c], acc0, 0, 0, 0);
      acc1 = __builtin_amdgcn_mfma_i32_16x16x64_i8(A[c], Bf[1][c], acc1, 0, 0, 0);
      acc2 = __builtin_amdgcn_mfma_i32_16x16x64_i8(A[c], Bf[2][c], acc2, 0, 0, 0);
      acc3 = __builtin_amdgcn_mfma_i32_16x16x64_i8(A[c], Bf[3][c], acc3, 0, 0, 0);
    }

    // --- sdot half: k-dwords [64,128), weights from LDS, state broadcast ---
    const int4* sp = (const int4*)qs[p];     // int4 index 16..31 = k>=256
    int a0 = 0, a1 = 0, a2 = 0, a3 = 0;
#pragma unroll
    for (int jj = 0; jj < 16; ++jj) {
      int4 W = wp[jj];
      int4 s = sp[16 + jj];
      a0 = SDOT4(W.x, s.x, a0);
      a1 = SDOT4(W.y, s.y, a1);
      a2 = SDOT4(W.z, s.z, a2);
      a3 = SDOT4(W.w, s.w, a3);
    }
    int sd = (a0 + a1) + (a2 + a3);

    // --- merge: lane's own n = tid is tile q=hi, reg 0, col l15 ---
    int vm = (hi & 1) ? ((hi & 2) ? acc3[0] : acc1[0])
                      : ((hi & 2) ? acc2[0] : acc0[0]);
    int acc = vm + sd;

    float a = g + (float)acc * dn;
    a = fminf(fmaxf(a, -15.f), 15.f);
    float e = __expf(2.f * a);           // tanh = 1 - 2/(e^(2a)+1)
    float s = fmaf(-2.f, __builtin_amdgcn_rcpf(e + 1.f), 1.f);
    signed char q8 = (signed char)(int)rintf(s * 127.f);
    qrow[(size_t)t * NST] = q8;
    qs[p ^ 1][tid] = q8;
    __syncthreads();
    g = g_n;
    p ^= 1;
  }
}

// ---------------------------------------------------------------------------
// k_out_i8 — the proven epilogue (what actually ran in every passing round).
// ---------------------------------------------------------------------------
__global__ __launch_bounds__(256) void k_out_i8(
    const signed char* __restrict__ qstates, const int* __restrict__ WoQ,
    const float* __restrict__ So, const float* __restrict__ b_out,
    float* __restrict__ y)
{
  __shared__ __align__(16) int sl[32 * 128];   // 16 KB
  int tid = threadIdx.x;
  size_t bt0 = (size_t)blockIdx.x * 32;
  const int4* gp = (const int4*)(qstates + bt0 * NST);
  int4* slp = (int4*)sl;
#pragma unroll
  for (int i = 0; i < 4; ++i) slp[tid + 256 * i] = gp[tid + 256 * i];
  __syncthreads();

  int a0 = tid & 63, gidx = tid >> 6;
  const int* slg = sl + gidx * 8 * 128;
  int acc0[8], acc1[8];
#pragma unroll
  for (int r = 0; r < 8; ++r) { acc0[r] = 0; acc1[r] = 0; }

  for (int j4 = 0; j4 < 32; ++j4) {
    int w00 = WoQ[(4 * j4 + 0) * 128 + a0];
    int w01 = WoQ[(4 * j4 + 0) * 128 + a0 + 64];
    int w10 = WoQ[(4 * j4 + 1) * 128 + a0];
    int w11 = WoQ[(4 * j4 + 1) * 128 + a0 + 64];
    int w20 = WoQ[(4 * j4 + 2) * 128 + a0];
    int w21 = WoQ[(4 * j4 + 2) * 128 + a0 + 64];
    int w30 = WoQ[(4 * j4 + 3) * 128 + a0];
    int w31 = WoQ[(4 * j4 + 3) * 128 + a0 + 64];
#pragma unroll
    for (int r = 0; r < 8; ++r) {
      int4 s = *(const int4*)&slg[r * 128 + 4 * j4];
      acc0[r] = SDOT4(w00, s.x, acc0[r]);
      acc1[r] = SDOT4(w01, s.x, acc1[r]);
      acc0[r] = SDOT4(w10, s.y, acc0[r]);
      acc1[r] = SDOT4(w11, s.y, acc1[r]);
      acc0[r] = SDOT4(w20, s.z, acc0[r]);
      acc1[r] = SDOT4(w21, s.z, acc1[r]);
      acc0[r] = SDOT4(w30, s.w, acc0[r]);
      acc1[r] = SDOT4(w31, s.w, acc1[r]);
    }
  }

  float s0 = So[a0], s1 = So[a0 + 64];
  float b0 = b_out[a0], b1 = b_out[a0 + 64];
#pragma unroll
  for (int r = 0; r < 8; ++r) {
    size_t rowb = (bt0 + gidx * 8 + r) * 128;
    y[rowb + a0]      = (float)acc0[r] * s0 + b0;
    y[rowb + a0 + 64] = (float)acc1[r] * s1 + b1;
  }
}

// ---------------------------------------------------------------------------
extern "C" void kernel_launch(void* const* d_in, const int* in_sizes, int n_in,
                              void* d_out, int out_size, void* d_ws, size_t ws_size,
                              hipStream_t stream) {
  const int*   w     = (const int*)d_in[0];
  const float* emb   = (const float*)d_in[1];
  const float* W_in  = (const float*)d_in[2];
  const float* b_in  = (const float*)d_in[3];
  const float* W_out = (const float*)d_in[4];
  const float* b_out = (const float*)d_in[5];
  float* y = (float*)d_out;

  char* ws = (char*)d_ws;
  float*       G       = (float*)ws;                        // 256 KB
  int*         WqT     = (int*)(ws + (256 << 10));          // 256 KB
  float*       Sd      = (float*)(ws + (512 << 10));        // 2 KB
  int*         WoQ     = (int*)(ws + (576 << 10));          // 64 KB
  float*       So      = (float*)(ws + (640 << 10));        // 0.5 KB
  int*         WsF     = (int*)(ws + (704 << 10));          // 256 KB frag-order
  signed char* qstates = (signed char*)(ws + (1024 << 10)); // 32 MB i8

  k_prep<<<896, 256, 0, stream>>>(emb, W_in, b_in, W_out, G, WqT, Sd, WoQ, So, WsF);
  k_rec <<<BATCH, 512, 0, stream>>>(w, G, WqT, WsF, Sd, qstates);
  k_out_i8<<<BATCH * TLEN / 32, 256, 0, stream>>>(qstates, WoQ, So, b_out, y);
}

// Round 6
// 337.644 us; speedup vs baseline: 1.1964x; 1.1964x over previous
//
#include <hip/hip_runtime.h>
#include <stdint.h>
#include <math.h>

#define NALPH 128
#define NEMB  128
#define NST   512
#define BATCH 256
#define TLEN  256
#define FANIN 640   // NEMB + NST

// No host/device-divergent preprocessor control flow (R11 lesson).
#define SDOT4(a, b, c) __builtin_amdgcn_sdot4((a), (b), (c), false)
typedef __attribute__((ext_vector_type(4))) int i32x4;

// ---------------------------------------------------------------------------
// k_prep (896 blocks x 256 thr):
//  [0,256)    G[tok*512+n] = b_in[n] + sum_e emb[tok,e]*W_in[n,e]  (fp32 exact)
//  [256,768)  W_s row-quant: WqT[kg*512+n] (k_rec layout); Sd[n]=mx/16129
//  [768,896)  W_out row-quant: WoQ[j*128+a] (k_out_i8 layout); So[a]=mx/16129
// ---------------------------------------------------------------------------
__global__ __launch_bounds__(256) void k_prep(
    const float* __restrict__ emb, const float* __restrict__ W_in,
    const float* __restrict__ b_in, const float* __restrict__ W_out,
    float* __restrict__ G, int* __restrict__ WqT, float* __restrict__ Sd,
    int* __restrict__ WoQ, float* __restrict__ So)
{
  int bid = blockIdx.x, tid = threadIdx.x;
  if (bid < 256) {
    int idx = bid * 256 + tid;           // tok*512 + n
    int tok = idx >> 9, n = idx & 511;
    const float* er = emb + tok * NEMB;
    const float* wr = W_in + (size_t)n * FANIN;
    float acc = b_in[n];
#pragma unroll 8
    for (int e = 0; e < NEMB; ++e) acc += er[e] * wr[e];
    G[idx] = acc;
  } else if (bid < 768) {
    int n = bid - 256;                   // W_s row
    __shared__ float smax[128];
    float lw[4]; float m = 0.f;
    if (tid < 128) {
      const float* wr = W_in + (size_t)n * FANIN + NEMB + tid * 4;
#pragma unroll
      for (int i = 0; i < 4; ++i) { lw[i] = wr[i]; m = fmaxf(m, fabsf(lw[i])); }
      smax[tid] = m;
    }
    __syncthreads();
    for (int s2 = 64; s2 > 0; s2 >>= 1) {
      if (tid < s2) smax[tid] = fmaxf(smax[tid], smax[tid + s2]);
      __syncthreads();
    }
    float mx = smax[0];
    if (tid < 128) {
      float r = 127.f / mx;
      uint32_t pk = 0;
#pragma unroll
      for (int i = 0; i < 4; ++i) {
        int qv = (int)rintf(lw[i] * r);
        qv = qv < -127 ? -127 : (qv > 127 ? 127 : qv);
        pk |= (uint32_t)(qv & 0xff) << (8 * i);
      }
      WqT[tid * NST + n] = (int)pk;      // k_rec reads WqT[j*512+n] coalesced
    }
    if (tid == 0) Sd[n] = mx / 16129.0f;
  } else {
    int a = bid - 768;                   // W_out row
    __shared__ float smax[128];
    float lw[4]; float m = 0.f;
    if (tid < 128) {
      const float* wr = W_out + (size_t)a * NST + tid * 4;
#pragma unroll
      for (int i = 0; i < 4; ++i) { lw[i] = wr[i]; m = fmaxf(m, fabsf(lw[i])); }
      smax[tid] = m;
    }
    __syncthreads();
    for (int s2 = 64; s2 > 0; s2 >>= 1) {
      if (tid < s2) smax[tid] = fmaxf(smax[tid], smax[tid + s2]);
      __syncthreads();
    }
    float mx = smax[0];
    if (tid < 128) {
      float r = 127.f / mx;
      uint32_t pk = 0;
#pragma unroll
      for (int i = 0; i < 4; ++i) {
        int qv = (int)rintf(lw[i] * r);
        qv = qv < -127 ? -127 : (qv > 127 ? 127 : qv);
        pk |= (uint32_t)(qv & 0xff) << (8 * i);
      }
      WoQ[tid * 128 + a] = (int)pk;      // k_out_i8 layout
    }
    if (tid == 0) So[a] = mx / 16129.0f;
  }
}

// ---------------------------------------------------------------------------
// k_rec R14 — R8 structure VERBATIM (proven 245 us) with ONE change:
// __launch_bounds__(512, 1) instead of (512, 2).
// Rationale: grid = 256 blocks on 256 CUs -> exactly 1 block/CU resident in
// EVERY measured round (OccupancyPercent ~23% = 8 waves/CU). The ",2" min-
// waves bound therefore bought nothing, but capped the unified register
// budget at 256/wave and drove the allocator to park wq[128] in AGPRs —
// v_dot4 cannot read AGPRs, so every step paid ~128 v_accvgpr_read moves
// (the measured ~750 cyc/step VALUBusy excess over the 512-cyc sdot floor).
// With min-waves=1 the budget is 512 regs/wave; wq[128] + ~40 live values
// fits in arch VGPRs with slack (and 170 VGPR still allows 3 waves/SIMD,
// above the 2/SIMD this 1-block/CU shape actually uses).
// Tell for success: reported VGPR_Count jumps to >=160.
// ---------------------------------------------------------------------------
__global__ __launch_bounds__(512, 1) void k_rec(
    const int* __restrict__ w, const float* __restrict__ G,
    const int* __restrict__ WqT, const float* __restrict__ Sd,
    signed char* __restrict__ qstates)
{
  __shared__ __align__(16) signed char qs[2][NST];
  int tid = threadIdx.x;
  int row = blockIdx.x;

  int wq[128];
#pragma unroll
  for (int j = 0; j < 128; ++j) wq[j] = WqT[j * NST + tid];  // coalesced
  float dn = Sd[tid];

  qs[0][tid] = 0;
  __syncthreads();

  const int* wr = w + row * TLEN;
  signed char* qrow = qstates + (size_t)row * TLEN * NST + tid;

  float g = G[wr[0] * NST + tid];
  int p = 0;
  for (int t = 0; t < TLEN; ++t) {
    int tok_n = (t < TLEN - 1) ? wr[t + 1] : 0;
    float g_n = G[tok_n * NST + tid];    // prefetch next step's fin
    const int4* sp = (const int4*)qs[p];
    int a0 = 0, a1 = 0, a2 = 0, a3 = 0;  // 4 independent chains
#pragma unroll
    for (int j = 0; j < 8; ++j) {
      int4 s0 = sp[4 * j + 0];
      int4 s1 = sp[4 * j + 1];
      int4 s2 = sp[4 * j + 2];
      int4 s3 = sp[4 * j + 3];
      a0 = SDOT4(wq[16 * j +  0], s0.x, a0);
      a1 = SDOT4(wq[16 * j +  1], s0.y, a1);
      a2 = SDOT4(wq[16 * j +  2], s0.z, a2);
      a3 = SDOT4(wq[16 * j +  3], s0.w, a3);
      a0 = SDOT4(wq[16 * j +  4], s1.x, a0);
      a1 = SDOT4(wq[16 * j +  5], s1.y, a1);
      a2 = SDOT4(wq[16 * j +  6], s1.z, a2);
      a3 = SDOT4(wq[16 * j +  7], s1.w, a3);
      a0 = SDOT4(wq[16 * j +  8], s2.x, a0);
      a1 = SDOT4(wq[16 * j +  9], s2.y, a1);
      a2 = SDOT4(wq[16 * j + 10], s2.z, a2);
      a3 = SDOT4(wq[16 * j + 11], s2.w, a3);
      a0 = SDOT4(wq[16 * j + 12], s3.x, a0);
      a1 = SDOT4(wq[16 * j + 13], s3.y, a1);
      a2 = SDOT4(wq[16 * j + 14], s3.z, a2);
      a3 = SDOT4(wq[16 * j + 15], s3.w, a3);
    }
    int acc = (a0 + a1) + (a2 + a3);
    float a = g + (float)acc * dn;
    a = fminf(fmaxf(a, -15.f), 15.f);
    float e = __expf(2.f * a);           // tanh = 1 - 2/(e^(2a)+1)
    float s = fmaf(-2.f, __builtin_amdgcn_rcpf(e + 1.f), 1.f);
    signed char q8 = (signed char)(int)rintf(s * 127.f);
    qrow[(size_t)t * NST] = q8;
    qs[p ^ 1][tid] = q8;
    __syncthreads();
    g = g_n;
    p ^= 1;
  }
}

// ---------------------------------------------------------------------------
// k_out_i8 — the proven epilogue (what actually ran in every passing round).
// ---------------------------------------------------------------------------
__global__ __launch_bounds__(256) void k_out_i8(
    const signed char* __restrict__ qstates, const int* __restrict__ WoQ,
    const float* __restrict__ So, const float* __restrict__ b_out,
    float* __restrict__ y)
{
  __shared__ __align__(16) int sl[32 * 128];   // 16 KB
  int tid = threadIdx.x;
  size_t bt0 = (size_t)blockIdx.x * 32;
  const int4* gp = (const int4*)(qstates + bt0 * NST);
  int4* slp = (int4*)sl;
#pragma unroll
  for (int i = 0; i < 4; ++i) slp[tid + 256 * i] = gp[tid + 256 * i];
  __syncthreads();

  int a0 = tid & 63, gidx = tid >> 6;
  const int* slg = sl + gidx * 8 * 128;
  int acc0[8], acc1[8];
#pragma unroll
  for (int r = 0; r < 8; ++r) { acc0[r] = 0; acc1[r] = 0; }

  for (int j4 = 0; j4 < 32; ++j4) {
    int w00 = WoQ[(4 * j4 + 0) * 128 + a0];
    int w01 = WoQ[(4 * j4 + 0) * 128 + a0 + 64];
    int w10 = WoQ[(4 * j4 + 1) * 128 + a0];
    int w11 = WoQ[(4 * j4 + 1) * 128 + a0 + 64];
    int w20 = WoQ[(4 * j4 + 2) * 128 + a0];
    int w21 = WoQ[(4 * j4 + 2) * 128 + a0 + 64];
    int w30 = WoQ[(4 * j4 + 3) * 128 + a0];
    int w31 = WoQ[(4 * j4 + 3) * 128 + a0 + 64];
#pragma unroll
    for (int r = 0; r < 8; ++r) {
      int4 s = *(const int4*)&slg[r * 128 + 4 * j4];
      acc0[r] = SDOT4(w00, s.x, acc0[r]);
      acc1[r] = SDOT4(w01, s.x, acc1[r]);
      acc0[r] = SDOT4(w10, s.y, acc0[r]);
      acc1[r] = SDOT4(w11, s.y, acc1[r]);
      acc0[r] = SDOT4(w20, s.z, acc0[r]);
      acc1[r] = SDOT4(w21, s.z, acc1[r]);
      acc0[r] = SDOT4(w30, s.w, acc0[r]);
      acc1[r] = SDOT4(w31, s.w, acc1[r]);
    }
  }

  float s0 = So[a0], s1 = So[a0 + 64];
  float b0 = b_out[a0], b1 = b_out[a0 + 64];
#pragma unroll
  for (int r = 0; r < 8; ++r) {
    size_t rowb = (bt0 + gidx * 8 + r) * 128;
    y[rowb + a0]      = (float)acc0[r] * s0 + b0;
    y[rowb + a0 + 64] = (float)acc1[r] * s1 + b1;
  }
}

// ---------------------------------------------------------------------------
extern "C" void kernel_launch(void* const* d_in, const int* in_sizes, int n_in,
                              void* d_out, int out_size, void* d_ws, size_t ws_size,
                              hipStream_t stream) {
  const int*   w     = (const int*)d_in[0];
  const float* emb   = (const float*)d_in[1];
  const float* W_in  = (const float*)d_in[2];
  const float* b_in  = (const float*)d_in[3];
  const float* W_out = (const float*)d_in[4];
  const float* b_out = (const float*)d_in[5];
  float* y = (float*)d_out;

  char* ws = (char*)d_ws;
  float*       G       = (float*)ws;                        // 256 KB
  int*         WqT     = (int*)(ws + (256 << 10));          // 256 KB
  float*       Sd      = (float*)(ws + (512 << 10));        // 2 KB
  int*         WoQ     = (int*)(ws + (576 << 10));          // 64 KB
  float*       So      = (float*)(ws + (640 << 10));        // 0.5 KB
  signed char* qstates = (signed char*)(ws + (1024 << 10)); // 32 MB i8

  k_prep<<<896, 256, 0, stream>>>(emb, W_in, b_in, W_out, G, WqT, Sd, WoQ, So);
  k_rec <<<BATCH, 512, 0, stream>>>(w, G, WqT, Sd, qstates);
  k_out_i8<<<BATCH * TLEN / 32, 256, 0, stream>>>(qstates, WoQ, So, b_out, y);
}

// Round 7
// 307.737 us; speedup vs baseline: 1.3126x; 1.0972x over previous
//
#include <hip/hip_runtime.h>
#include <stdint.h>
#include <math.h>

#define NALPH 128
#define NEMB  128
#define NST   512
#define BATCH 256
#define TLEN  256
#define FANIN 640   // NEMB + NST

// No host/device-divergent preprocessor control flow (R11 lesson).
#define SDOT4(a, b, c) __builtin_amdgcn_sdot4((a), (b), (c), false)
typedef __attribute__((ext_vector_type(4))) int i32x4;

// ---------------------------------------------------------------------------
// k_prep (896 blocks x 256 thr):
//  [0,256)    G[tok*512+n] = b_in[n] + sum_e emb[tok,e]*W_in[n,e]  (fp32 exact)
//  [256,768)  W_s row-quant: WqT[kg*512+n] (k_rec layout); Sd[n]=mx/16129
//  [768,896)  W_out row-quant: WoQ[j*128+a] (fallback layout) AND MFMA B-frag
//             order WoF[((ta*8+c)*64+lane)*4+d]; So[a]=mx/16129
// Frag mapping (dword kd of a 512B row r): c=kd>>4, hi=(kd>>2)&3, d=kd&3,
// lane=hi*16+(r&15), tile=r>>4. This exact formula was hardware-validated
// bit-exactly by R12's k_rec (WsF path, absmax 0.009765625).
// ---------------------------------------------------------------------------
__global__ __launch_bounds__(256) void k_prep(
    const float* __restrict__ emb, const float* __restrict__ W_in,
    const float* __restrict__ b_in, const float* __restrict__ W_out,
    float* __restrict__ G, int* __restrict__ WqT, float* __restrict__ Sd,
    int* __restrict__ WoQ, int* __restrict__ WoF, float* __restrict__ So)
{
  int bid = blockIdx.x, tid = threadIdx.x;
  if (bid < 256) {
    int idx = bid * 256 + tid;           // tok*512 + n
    int tok = idx >> 9, n = idx & 511;
    const float* er = emb + tok * NEMB;
    const float* wr = W_in + (size_t)n * FANIN;
    float acc = b_in[n];
#pragma unroll 8
    for (int e = 0; e < NEMB; ++e) acc += er[e] * wr[e];
    G[idx] = acc;
  } else if (bid < 768) {
    int n = bid - 256;                   // W_s row
    __shared__ float smax[128];
    float lw[4]; float m = 0.f;
    if (tid < 128) {
      const float* wr = W_in + (size_t)n * FANIN + NEMB + tid * 4;
#pragma unroll
      for (int i = 0; i < 4; ++i) { lw[i] = wr[i]; m = fmaxf(m, fabsf(lw[i])); }
      smax[tid] = m;
    }
    __syncthreads();
    for (int s2 = 64; s2 > 0; s2 >>= 1) {
      if (tid < s2) smax[tid] = fmaxf(smax[tid], smax[tid + s2]);
      __syncthreads();
    }
    float mx = smax[0];
    if (tid < 128) {
      float r = 127.f / mx;
      uint32_t pk = 0;
#pragma unroll
      for (int i = 0; i < 4; ++i) {
        int qv = (int)rintf(lw[i] * r);
        qv = qv < -127 ? -127 : (qv > 127 ? 127 : qv);
        pk |= (uint32_t)(qv & 0xff) << (8 * i);
      }
      WqT[tid * NST + n] = (int)pk;      // k_rec reads WqT[j*512+n] coalesced
    }
    if (tid == 0) Sd[n] = mx / 16129.0f;
  } else {
    int a = bid - 768;                   // W_out row
    __shared__ float smax[128];
    float lw[4]; float m = 0.f;
    if (tid < 128) {
      const float* wr = W_out + (size_t)a * NST + tid * 4;
#pragma unroll
      for (int i = 0; i < 4; ++i) { lw[i] = wr[i]; m = fmaxf(m, fabsf(lw[i])); }
      smax[tid] = m;
    }
    __syncthreads();
    for (int s2 = 64; s2 > 0; s2 >>= 1) {
      if (tid < s2) smax[tid] = fmaxf(smax[tid], smax[tid + s2]);
      __syncthreads();
    }
    float mx = smax[0];
    if (tid < 128) {
      float r = 127.f / mx;
      uint32_t pk = 0;
#pragma unroll
      for (int i = 0; i < 4; ++i) {
        int qv = (int)rintf(lw[i] * r);
        qv = qv < -127 ? -127 : (qv > 127 ? 127 : qv);
        pk |= (uint32_t)(qv & 0xff) << (8 * i);
      }
      WoQ[tid * 128 + a] = (int)pk;      // fallback layout (unused this round)
      int kd = tid;
      int c = kd >> 4, hi = (kd >> 2) & 3, d = kd & 3;
      int lane = hi * 16 + (a & 15), ta = a >> 4;
      WoF[(((ta * 8 + c) * 64) + lane) * 4 + d] = (int)pk;  // MFMA B-frag
    }
    if (tid == 0) So[a] = mx / 16129.0f;
  }
}

// ---------------------------------------------------------------------------
// k_rec — R14 verbatim (proven 245 us). Register/AGPR-resident W_s sdot loop;
// the allocator's AGPR parking is accepted as unavoidable (R9/R10/R14 all
// failed to move it; step wall ~2300 cyc is structural across 4 designs).
// ---------------------------------------------------------------------------
__global__ __launch_bounds__(512, 1) void k_rec(
    const int* __restrict__ w, const float* __restrict__ G,
    const int* __restrict__ WqT, const float* __restrict__ Sd,
    signed char* __restrict__ qstates)
{
  __shared__ __align__(16) signed char qs[2][NST];
  int tid = threadIdx.x;
  int row = blockIdx.x;

  int wq[128];
#pragma unroll
  for (int j = 0; j < 128; ++j) wq[j] = WqT[j * NST + tid];  // coalesced
  float dn = Sd[tid];

  qs[0][tid] = 0;
  __syncthreads();

  const int* wr = w + row * TLEN;
  signed char* qrow = qstates + (size_t)row * TLEN * NST + tid;

  float g = G[wr[0] * NST + tid];
  int p = 0;
  for (int t = 0; t < TLEN; ++t) {
    int tok_n = (t < TLEN - 1) ? wr[t + 1] : 0;
    float g_n = G[tok_n * NST + tid];    // prefetch next step's fin
    const int4* sp = (const int4*)qs[p];
    int a0 = 0, a1 = 0, a2 = 0, a3 = 0;  // 4 independent chains
#pragma unroll
    for (int j = 0; j < 8; ++j) {
      int4 s0 = sp[4 * j + 0];
      int4 s1 = sp[4 * j + 1];
      int4 s2 = sp[4 * j + 2];
      int4 s3 = sp[4 * j + 3];
      a0 = SDOT4(wq[16 * j +  0], s0.x, a0);
      a1 = SDOT4(wq[16 * j +  1], s0.y, a1);
      a2 = SDOT4(wq[16 * j +  2], s0.z, a2);
      a3 = SDOT4(wq[16 * j +  3], s0.w, a3);
      a0 = SDOT4(wq[16 * j +  4], s1.x, a0);
      a1 = SDOT4(wq[16 * j +  5], s1.y, a1);
      a2 = SDOT4(wq[16 * j +  6], s1.z, a2);
      a3 = SDOT4(wq[16 * j +  7], s1.w, a3);
      a0 = SDOT4(wq[16 * j +  8], s2.x, a0);
      a1 = SDOT4(wq[16 * j +  9], s2.y, a1);
      a2 = SDOT4(wq[16 * j + 10], s2.z, a2);
      a3 = SDOT4(wq[16 * j + 11], s2.w, a3);
      a0 = SDOT4(wq[16 * j + 12], s3.x, a0);
      a1 = SDOT4(wq[16 * j + 13], s3.y, a1);
      a2 = SDOT4(wq[16 * j + 14], s3.z, a2);
      a3 = SDOT4(wq[16 * j + 15], s3.w, a3);
    }
    int acc = (a0 + a1) + (a2 + a3);
    float a = g + (float)acc * dn;
    a = fminf(fmaxf(a, -15.f), 15.f);
    float e = __expf(2.f * a);           // tanh = 1 - 2/(e^(2a)+1)
    float s = fmaf(-2.f, __builtin_amdgcn_rcpf(e + 1.f), 1.f);
    signed char q8 = (signed char)(int)rintf(s * 127.f);
    qrow[(size_t)t * NST] = q8;
    qs[p ^ 1][tid] = q8;
    __syncthreads();
    g = g_n;
    p ^= 1;
  }
}

// ---------------------------------------------------------------------------
// k_out_mfma — NOW ACTUALLY LAUNCHED (R11 found it never ran before: the
// host-side #if took the fallback branch in every prior session).
// y[bt,a] = b_out[a] + So[a]*sum_k qs[bt,k]*qw[a,k].
// 1024 blocks x 256 thr (4 waves); wave handles 16 bt-rows x 128 a.
// A[m=l15][k=hi*16+c*64+0..15] (same pattern R12 validated), B from WoF
// (same frag formula R12 validated), D: col=l15 (a), row=hi*4+r (m89).
// Integer dots identical to k_out_i8 -> bit-identical y, absmax unchanged.
// ---------------------------------------------------------------------------
__global__ __launch_bounds__(256) void k_out_mfma(
    const signed char* __restrict__ qstates, const int* __restrict__ WoF,
    const float* __restrict__ So, const float* __restrict__ b_out,
    float* __restrict__ y)
{
  int tid = threadIdx.x;
  int lane = tid & 63, wv = tid >> 6;
  int l15 = lane & 15, hi = lane >> 4;
  size_t bt0 = (size_t)blockIdx.x * 64 + (size_t)wv * 16;

  const signed char* abase = qstates + (bt0 + l15) * NST + hi * 16;
  i32x4 A[8];
#pragma unroll
  for (int c = 0; c < 8; ++c) A[c] = *(const i32x4*)(abase + c * 64);

  const i32x4* wf = (const i32x4*)WoF;
#pragma unroll
  for (int ta = 0; ta < 8; ++ta) {
    const i32x4* bbase = wf + (size_t)ta * 8 * 64 + lane;
    i32x4 acc = {0, 0, 0, 0};
#pragma unroll
    for (int c = 0; c < 8; ++c)
      acc = __builtin_amdgcn_mfma_i32_16x16x64_i8(A[c], bbase[c * 64], acc, 0, 0, 0);
    int a = ta * 16 + l15;
    float s = So[a], b = b_out[a];
    float* yb = y + (bt0 + hi * 4) * 128 + a;
#pragma unroll
    for (int r = 0; r < 4; ++r) yb[(size_t)r * 128] = (float)acc[r] * s + b;
  }
}

// ---------------------------------------------------------------------------
// k_out_i8 — proven fallback, kept compiled for quick revert (not launched).
// ---------------------------------------------------------------------------
__global__ __launch_bounds__(256) void k_out_i8(
    const signed char* __restrict__ qstates, const int* __restrict__ WoQ,
    const float* __restrict__ So, const float* __restrict__ b_out,
    float* __restrict__ y)
{
  __shared__ __align__(16) int sl[32 * 128];   // 16 KB
  int tid = threadIdx.x;
  size_t bt0 = (size_t)blockIdx.x * 32;
  const int4* gp = (const int4*)(qstates + bt0 * NST);
  int4* slp = (int4*)sl;
#pragma unroll
  for (int i = 0; i < 4; ++i) slp[tid + 256 * i] = gp[tid + 256 * i];
  __syncthreads();

  int a0 = tid & 63, gidx = tid >> 6;
  const int* slg = sl + gidx * 8 * 128;
  int acc0[8], acc1[8];
#pragma unroll
  for (int r = 0; r < 8; ++r) { acc0[r] = 0; acc1[r] = 0; }

  for (int j4 = 0; j4 < 32; ++j4) {
    int w00 = WoQ[(4 * j4 + 0) * 128 + a0];
    int w01 = WoQ[(4 * j4 + 0) * 128 + a0 + 64];
    int w10 = WoQ[(4 * j4 + 1) * 128 + a0];
    int w11 = WoQ[(4 * j4 + 1) * 128 + a0 + 64];
    int w20 = WoQ[(4 * j4 + 2) * 128 + a0];
    int w21 = WoQ[(4 * j4 + 2) * 128 + a0 + 64];
    int w30 = WoQ[(4 * j4 + 3) * 128 + a0];
    int w31 = WoQ[(4 * j4 + 3) * 128 + a0 + 64];
#pragma unroll
    for (int r = 0; r < 8; ++r) {
      int4 s = *(const int4*)&slg[r * 128 + 4 * j4];
      acc0[r] = SDOT4(w00, s.x, acc0[r]);
      acc1[r] = SDOT4(w01, s.x, acc1[r]);
      acc0[r] = SDOT4(w10, s.y, acc0[r]);
      acc1[r] = SDOT4(w11, s.y, acc1[r]);
      acc0[r] = SDOT4(w20, s.z, acc0[r]);
      acc1[r] = SDOT4(w21, s.z, acc1[r]);
      acc0[r] = SDOT4(w30, s.w, acc0[r]);
      acc1[r] = SDOT4(w31, s.w, acc1[r]);
    }
  }

  float s0 = So[a0], s1 = So[a0 + 64];
  float b0 = b_out[a0], b1 = b_out[a0 + 64];
#pragma unroll
  for (int r = 0; r < 8; ++r) {
    size_t rowb = (bt0 + gidx * 8 + r) * 128;
    y[rowb + a0]      = (float)acc0[r] * s0 + b0;
    y[rowb + a0 + 64] = (float)acc1[r] * s1 + b1;
  }
}

// ---------------------------------------------------------------------------
extern "C" void kernel_launch(void* const* d_in, const int* in_sizes, int n_in,
                              void* d_out, int out_size, void* d_ws, size_t ws_size,
                              hipStream_t stream) {
  const int*   w     = (const int*)d_in[0];
  const float* emb   = (const float*)d_in[1];
  const float* W_in  = (const float*)d_in[2];
  const float* b_in  = (const float*)d_in[3];
  const float* W_out = (const float*)d_in[4];
  const float* b_out = (const float*)d_in[5];
  float* y = (float*)d_out;

  char* ws = (char*)d_ws;
  float*       G       = (float*)ws;                        // 256 KB
  int*         WqT     = (int*)(ws + (256 << 10));          // 256 KB
  float*       Sd      = (float*)(ws + (512 << 10));        // 2 KB
  int*         WoQ     = (int*)(ws + (576 << 10));          // 64 KB
  float*       So      = (float*)(ws + (640 << 10));        // 0.5 KB
  int*         WoF     = (int*)(ws + (704 << 10));          // 32 KB frag-order
  signed char* qstates = (signed char*)(ws + (1024 << 10)); // 32 MB i8

  k_prep<<<896, 256, 0, stream>>>(emb, W_in, b_in, W_out, G, WqT, Sd, WoQ, WoF, So);
  k_rec <<<BATCH, 512, 0, stream>>>(w, G, WqT, Sd, qstates);
  k_out_mfma<<<BATCH * TLEN / 64, 256, 0, stream>>>(qstates, WoF, So, b_out, y);
}